// Round 8
// baseline (5283.612 us; speedup 1.0000x reference)
//
#include <hip/hip_runtime.h>

// 2-layer LSTM (NS=51), B=8192, T=2048, future=0.
// 4 waves x 2 M-tiles (32x32x16 f16 MFMA, operand-swapped: A=weights in VGPR,
// B=state in LDS). State rows use additive pseudo-swizzle so every LDS access
// is base-reg + compile-time offset. Bias folded into a constant-1 k-slot.
// Per step: GEMM1 -> GEMM2(h2-half, prefetched) -> update1 -> barrier ->
// GEMM2(h1-half) -> y-store -> update2 -> barrier.

#define TLEN 2048
#define BTOT 8192
#define NSZ  51
#define NB   32
#define NTHREADS 256       // 4 waves
#define ROWB 576           // bytes per state row (512 data + swizzle headroom)
#define BUFB (NB * ROWB)   // 18 KB per buffer

// Row layout (lb = logical byte, k = lb/2 fp16 index):
//  lb [0,204)   h1 hi/lo pairs (k[0,102), u = k>>1, hi even / lo odd)
//  lb [204,208) x hi/lo        (k 102,103)
//  lb [208,210) const 1.0      (k 104, bias slot)
//  lb [210,224) zero pad       (k 105-111)
//  lb [224,428) h2 hi/lo pairs (k[112,214))
//  lb [428,448) zero pad       (k 214-223)
// phys(row, lb) = row*ROWB + ((row&7)<<4) + lb   (8-slot bank spread)

typedef _Float16 half8  __attribute__((ext_vector_type(8)));
typedef __fp16   fp16x2 __attribute__((ext_vector_type(2)));
typedef float    f32x16 __attribute__((ext_vector_type(16)));

// hi/lo fp16 split of a float, packed into one u32 (hi in low half).
// cvt_pkrtz rounds toward zero; v - (float)hi is exact in fp32, so the
// lo term captures the residual to ~2^-22 relative.
__device__ __forceinline__ unsigned pack_hilo(float v) {
    const fp16x2 ph = __builtin_amdgcn_cvt_pkrtz(v, 0.0f);
    const float  hi = (float)ph[0];
    const fp16x2 pk = __builtin_amdgcn_cvt_pkrtz(v, v - hi);
    return __builtin_bit_cast(unsigned, pk);
}

__global__ __launch_bounds__(NTHREADS, 1) void lstm2_kernel(
    const float* __restrict__ xg,    // [B][T]
    const float* __restrict__ wih1,  // [204][1]
    const float* __restrict__ whh1,  // [204][51]
    const float* __restrict__ bih1, const float* __restrict__ bhh1,
    const float* __restrict__ wih2,  // [204][51]
    const float* __restrict__ whh2,  // [204][51]
    const float* __restrict__ bih2, const float* __restrict__ bhh2,
    const float* __restrict__ wlin,  // [51]
    const float* __restrict__ blin,  // [1]
    float* __restrict__ out)         // [B][T]
{
    __shared__ char hs[2 * BUFB];    // 36 KB ping-pong state

    const int tid  = threadIdx.x;
    const int wv   = tid >> 6;       // wave 0..3
    const int lane = tid & 63;
    const int nloc = lane & 31;      // batch column / state row
    const int h4   = lane >> 5;      // k-octet selector
    const int b0   = blockIdx.x * NB;

    for (int i = tid; i < 2 * BUFB / 4; i += NTHREADS) ((int*)hs)[i] = 0;

    const float LOG2E = 1.4426950408889634f;

    // ---- stationary weight A-fragments for up to 2 tiles ----
    half8 A1[2][7], A2[2][14];
#pragma unroll
    for (int ti = 0; ti < 2; ++ti) {
        const int tile = 2 * wv + ti;
        const int n = tile * 32 + nloc;               // interleaved gate row 4u+g
        const int Rrow = (n < 204) ? 51 * (n & 3) + (n >> 2) : 0;
        const float am = ((n & 3) == 2) ? (-2.0f * LOG2E) : (-LOG2E);
        const float b1 = (n < 204) ? am * (bih1[Rrow] + bhh1[Rrow]) : 0.0f;
        float b2 = 0.0f;
        if (n < 204)       b2 = am * (bih2[Rrow] + bhh2[Rrow]);
        else if (n == 204) b2 = blin[0];
#pragma unroll
        for (int s = 0; s < 7; ++s) {
            half8 v;
#pragma unroll
            for (int j = 0; j < 8; ++j) {
                const int k = 16 * s + 8 * h4 + j;
                float w = 0.0f;
                if (n < 204) {
                    if (k < 102)       w = am * whh1[Rrow * 51 + (k >> 1)];
                    else if (k < 104)  w = am * wih1[Rrow];
                    else if (k == 104) w = b1;
                }
                v[j] = (_Float16)w;
            }
            A1[ti][s] = v;
        }
#pragma unroll
        for (int s = 0; s < 14; ++s) {
            half8 v;
#pragma unroll
            for (int j = 0; j < 8; ++j) {
                const int k = 16 * s + 8 * h4 + j;
                float w = 0.0f;
                if (n < 204) {
                    if (k < 102)                  w = am * wih2[Rrow * 51 + (k >> 1)];
                    else if (k == 104)            w = b2;
                    else if (k >= 112 && k < 214) w = am * whh2[Rrow * 51 + ((k - 112) >> 1)];
                } else if (n == 204) {            // y row: wlin . h2 + blin
                    if (k == 104)                 w = b2;
                    else if (k >= 112 && k < 214) w = wlin[(k - 112) >> 1];
                }
                v[j] = (_Float16)w;
            }
            A2[ti][s] = v;
        }
    }

    float c1[2][4] = {}, c2[2][4] = {};

    const int myoff = nloc * ROWB + ((nloc & 7) << 4);
    char* const P0 = hs + myoff;
    char* const P1 = hs + BUFB + myoff;

    __syncthreads();                 // zero-init visible
    if (tid < NB) {
        char* r0 = hs + tid * ROWB + ((tid & 7) << 4);
        *(unsigned short*)(r0 + 208) = 0x3C00;          // const 1.0, buf0
        *(unsigned short*)(r0 + BUFB + 208) = 0x3C00;   // const 1.0, buf1
        const float xv = xg[(size_t)(b0 + tid) * TLEN]; // x_0
        *(unsigned*)(r0 + 204) = pack_hilo(xv);
    }
    __syncthreads();

    auto update_layer = [&](f32x16 (&A)[2], float (&C)[2][4], char* base, int boff) {
#pragma unroll
        for (int ti = 0; ti < 2; ++ti) {
#pragma unroll
            for (int m = 0; m < 4; ++m) {
                const int u = 8 * (2 * wv + ti) + 2 * m + h4;
                if (u < NSZ) {
                    const float gi = __builtin_amdgcn_rcpf(1.0f + __builtin_amdgcn_exp2f(A[ti][4*m+0]));
                    const float gf = __builtin_amdgcn_rcpf(1.0f + __builtin_amdgcn_exp2f(A[ti][4*m+1]));
                    const float gt = fmaf(2.0f, __builtin_amdgcn_rcpf(1.0f + __builtin_amdgcn_exp2f(A[ti][4*m+2])), -1.0f);
                    const float go = __builtin_amdgcn_rcpf(1.0f + __builtin_amdgcn_exp2f(A[ti][4*m+3]));
                    const float cn = fmaf(gf, C[ti][m], gi * gt);
                    C[ti][m] = cn;
                    const float ee = __builtin_amdgcn_exp2f(-2.8853900817779268f * cn);
                    const float th = fmaf(2.0f, __builtin_amdgcn_rcpf(1.0f + ee), -1.0f);
                    const float hv = go * th;
                    *(unsigned*)(base + boff + 4 * u) = pack_hilo(hv);
                }
            }
        }
    };

    auto step = [&](char* Sp, char* Sq, int t) {
        // early x_{t+1} load (wave 3, lanes 0-31 own batch rows)
        float xn = 0.0f;
        if (wv == 3 && h4 == 0 && t + 1 < TLEN)
            xn = xg[(size_t)(b0 + nloc) * TLEN + t + 1];

        // GEMM1: k[0,112) of Sp (h1_{t-1}, x_t, bias-slot)
        half8 bf[7];
#pragma unroll
        for (int s = 0; s < 7; ++s)
            bf[s] = *(const half8*)(Sp + 32 * s + 16 * h4);
        f32x16 acc[2];
#pragma unroll
        for (int ti = 0; ti < 2; ++ti) {
            f32x16 a = {};
            if (2 * wv + ti < 7) {
#pragma unroll
                for (int s = 0; s < 7; ++s)
                    a = __builtin_amdgcn_mfma_f32_32x32x16_f16(A1[ti][s], bf[s], a, 0, 0, 0);
            }
            acc[ti] = a;
        }

        // GEMM2 h2-half (h2_{t-1} in Sq lb 224+), independent of update1
        half8 bh[7];
#pragma unroll
        for (int s = 0; s < 7; ++s)
            bh[s] = *(const half8*)(Sq + 224 + 32 * s + 16 * h4);
        f32x16 acc2[2];
#pragma unroll
        for (int ti = 0; ti < 2; ++ti) {
            f32x16 a = {};
            if (2 * wv + ti < 7) {
#pragma unroll
                for (int s = 0; s < 7; ++s)
                    a = __builtin_amdgcn_mfma_f32_32x32x16_f16(A2[ti][7 + s], bh[s], a, 0, 0, 0);
            }
            acc2[ti] = a;
        }

        // layer-1 update -> h1_t into Sq lb [0,204)
        update_layer(acc, c1, Sq, 0);
        if (wv == 3 && h4 == 0 && t + 1 < TLEN)
            *(unsigned*)(Sq + 204) = pack_hilo(xn);
        __syncthreads();

        // GEMM2 h1-half: k[0,112) of Sq (h1_t; x slot has zero weights)
        half8 bg[7];
#pragma unroll
        for (int s = 0; s < 7; ++s)
            bg[s] = *(const half8*)(Sq + 32 * s + 16 * h4);
#pragma unroll
        for (int ti = 0; ti < 2; ++ti) {
            if (2 * wv + ti < 7) {
#pragma unroll
                for (int s = 0; s < 7; ++s)
                    acc2[ti] = __builtin_amdgcn_mfma_f32_32x32x16_f16(A2[ti][s], bg[s], acc2[ti], 0, 0, 0);
            }
        }

        // y row (n=204 = tile 6 local row 12 -> wave 3, h4==1, q=4): y_{t-1}
        if (wv == 3 && h4 == 1 && t > 0)
            out[(size_t)(b0 + nloc) * TLEN + (t - 1)] = acc2[0][4];

        // layer-2 update -> h2_t into Sp lb 224+ (next step's Sq)
        update_layer(acc2, c2, Sp, 224);
        __syncthreads();
    };

    for (int t2 = 0; t2 < TLEN; t2 += 2) {
        step(P0, P1, t2);
        step(P1, P0, t2 + 1);
    }

    // final y_{T-1} = blin + wlin . h2_{T-1} (h2_2047 lives in buffer 1)
    if (tid < NB) {
        const char* r1 = hs + BUFB + tid * ROWB + ((tid & 7) << 4);
        float s = blin[0];
        for (int u = 0; u < NSZ; ++u) {
            const unsigned pk = *(const unsigned*)(r1 + 224 + 4 * u);
            const float hh = (float)__builtin_bit_cast(_Float16, (unsigned short)(pk & 0xffffu));
            const float hl = (float)__builtin_bit_cast(_Float16, (unsigned short)(pk >> 16));
            s = fmaf(wlin[u], hh + hl, s);
        }
        out[(size_t)(b0 + tid) * TLEN + (TLEN - 1)] = s;
    }
}

extern "C" void kernel_launch(void* const* d_in, const int* in_sizes, int n_in,
                              void* d_out, int out_size, void* d_ws, size_t ws_size,
                              hipStream_t stream) {
    (void)in_sizes; (void)n_in; (void)d_ws; (void)ws_size; (void)out_size;
    const float* xg   = (const float*)d_in[0];
    const float* wih1 = (const float*)d_in[1];
    const float* whh1 = (const float*)d_in[2];
    const float* bih1 = (const float*)d_in[3];
    const float* bhh1 = (const float*)d_in[4];
    const float* wih2 = (const float*)d_in[5];
    const float* whh2 = (const float*)d_in[6];
    const float* bih2 = (const float*)d_in[7];
    const float* bhh2 = (const float*)d_in[8];
    const float* wlin = (const float*)d_in[9];
    const float* blin = (const float*)d_in[10];
    // d_in[11] = future (static 0) -- ignored
    lstm2_kernel<<<dim3(BTOT / NB), dim3(NTHREADS), 0, stream>>>(
        xg, wih1, whh1, bih1, bhh1, wih2, whh2, bih2, bhh2, wlin, blin,
        (float*)d_out);
}

// Round 10
// 3378.160 us; speedup vs baseline: 1.5641x; 1.5641x over previous
//
#include <hip/hip_runtime.h>

// 2-layer LSTM (NS=51), B=8192, T=2048, future=0.
// Two-stage layer pipeline: waves 0-6 = layer 1 (GEMM1+update1), waves 7-13 =
// layer 2 (GEMM2+y+update2), running DIFFERENT time steps concurrently.
// Slot s: A does step s layer-1; B does step s-1 layer-2. One ping-pong state
// buffer pair, ONE barrier per slot. 32x32x16 f16 MFMA, weights stationary in
// VGPR (A:28, B:56 regs), state in LDS with additive pseudo-swizzle so every
// access is base + compile-time offset. Bias via constant-1 k-slot.
// Precision: h,x as fp16 hi+lo pairs, fp32 MFMA accum, fp32 activations.

#define TLEN 2048
#define BTOT 8192
#define NSZ  51
#define NB   32
#define NWAVES 14
#define NTHREADS (NWAVES * 64)   // 896
#define ROWB 576                 // bytes per state row
#define BUFB (NB * ROWB)         // 18 KB per buffer

// Row layout (lb = logical byte, k = lb/2 fp16 index):
//  lb [0,204)   h1 hi/lo pairs (k[0,102), u = k>>1)
//  lb [204,208) x hi/lo        (k 102,103)
//  lb [208,210) const 1.0      (k 104, bias slot)
//  lb [210,224) zero pad       (k 105-111)
//  lb [224,428) h2 hi/lo pairs (k[112,214))
//  lb [428,448) zero pad       (k 214-223)
// phys(row, lb) = row*ROWB + ((row&7)<<4) + lb

typedef _Float16 half8  __attribute__((ext_vector_type(8)));
typedef __fp16   fp16x2 __attribute__((ext_vector_type(2)));
typedef float    f32x16 __attribute__((ext_vector_type(16)));

__device__ __forceinline__ unsigned pack_hilo(float v) {
    const fp16x2 ph = __builtin_amdgcn_cvt_pkrtz(v, 0.0f);
    const float  hi = (float)ph[0];
    const fp16x2 pk = __builtin_amdgcn_cvt_pkrtz(v, v - hi);
    return __builtin_bit_cast(unsigned, pk);
}

__global__ __launch_bounds__(NTHREADS, 4) void lstm2_kernel(
    const float* __restrict__ xg,    // [B][T]
    const float* __restrict__ wih1,  // [204][1]
    const float* __restrict__ whh1,  // [204][51]
    const float* __restrict__ bih1, const float* __restrict__ bhh1,
    const float* __restrict__ wih2,  // [204][51]
    const float* __restrict__ whh2,  // [204][51]
    const float* __restrict__ bih2, const float* __restrict__ bhh2,
    const float* __restrict__ wlin,  // [51]
    const float* __restrict__ blin,  // [1]
    float* __restrict__ out)         // [B][T]
{
    __shared__ char hs[2 * BUFB];    // 36 KB ping-pong state

    const int tid  = threadIdx.x;
    const int wv   = tid >> 6;       // wave 0..13
    const int lane = tid & 63;
    const int nloc = lane & 31;      // batch column / state row
    const int h4   = lane >> 5;      // k-octet selector
    const int b0   = blockIdx.x * NB;
    const bool isA = (wv < 7);       // layer-1 group
    const int tile = isA ? wv : wv - 7;

    for (int i = tid; i < 2 * BUFB / 4; i += NTHREADS) ((int*)hs)[i] = 0;

    const float LOG2E = 1.4426950408889634f;
    const int n = tile * 32 + nloc;               // interleaved gate row 4u+g
    const int Rrow = (n < 204) ? 51 * (n & 3) + (n >> 2) : 0;
    const float am = ((n & 3) == 2) ? (-2.0f * LOG2E) : (-LOG2E);

    // ---- stationary weight fragments: A-waves W[0..6]=A1, B-waves W[0..13]=A2
    half8 W[14];
#pragma unroll
    for (int sN = 0; sN < 14; ++sN) {
        half8 v;
#pragma unroll
        for (int j = 0; j < 8; ++j) {
            const int k = 16 * sN + 8 * h4 + j;
            float w = 0.0f;
            if (isA) {
                if (sN < 7 && n < 204) {
                    if (k < 102)       w = am * whh1[Rrow * 51 + (k >> 1)];
                    else if (k < 104)  w = am * wih1[Rrow];
                    else if (k == 104) w = am * (bih1[Rrow] + bhh1[Rrow]);
                }
            } else {
                if (n < 204) {
                    if (k < 102)                  w = am * wih2[Rrow * 51 + (k >> 1)];
                    else if (k == 104)            w = am * (bih2[Rrow] + bhh2[Rrow]);
                    else if (k >= 112 && k < 214) w = am * whh2[Rrow * 51 + ((k - 112) >> 1)];
                } else if (n == 204) {            // y row: blin + wlin . h2
                    if (k == 104)                 w = blin[0];
                    else if (k >= 112 && k < 214) w = wlin[(k - 112) >> 1];
                }
            }
            v[j] = (_Float16)w;
        }
        W[sN] = v;
    }

    float cst[4] = {0, 0, 0, 0};     // c1 (A-waves) or c2 (B-waves)

    const int myoff = nloc * ROWB + ((nloc & 7) << 4);
    char* Rd = hs + myoff;           // slot-0 read buffer (buf 0)
    char* Wr = hs + BUFB + myoff;    // slot-0 write buffer (buf 1)

    __syncthreads();                 // zero-init visible
    if (tid < NB) {
        char* r0 = hs + tid * ROWB + ((tid & 7) << 4);
        *(unsigned short*)(r0 + 208) = 0x3C00;          // const 1.0, buf0
        *(unsigned short*)(r0 + BUFB + 208) = 0x3C00;   // const 1.0, buf1
        const float xv = xg[(size_t)(b0 + tid) * TLEN]; // x_0 -> buf0
        *(unsigned*)(r0 + 204) = pack_hilo(xv);
    }
    __syncthreads();

    // per-wave update: 4 accumulator quads -> 4 (b,u) tasks (guarded u<51)
    auto update_layer = [&](const f32x16& A, char* base, int boff) {
#pragma unroll
        for (int m = 0; m < 4; ++m) {
            const int u = 8 * tile + 2 * m + h4;
            if (u < NSZ) {
                const float gi = __builtin_amdgcn_rcpf(1.0f + __builtin_amdgcn_exp2f(A[4*m+0]));
                const float gf = __builtin_amdgcn_rcpf(1.0f + __builtin_amdgcn_exp2f(A[4*m+1]));
                const float gt = fmaf(2.0f, __builtin_amdgcn_rcpf(1.0f + __builtin_amdgcn_exp2f(A[4*m+2])), -1.0f);
                const float go = __builtin_amdgcn_rcpf(1.0f + __builtin_amdgcn_exp2f(A[4*m+3]));
                const float cn = fmaf(gf, cst[m], gi * gt);
                cst[m] = cn;
                const float ee = __builtin_amdgcn_exp2f(-2.8853900817779268f * cn);
                const float th = fmaf(2.0f, __builtin_amdgcn_rcpf(1.0f + ee), -1.0f);
                const float hv = go * th;
                *(unsigned*)(base + boff + 4 * u) = pack_hilo(hv);
            }
        }
    };

    for (int s = 0; s <= TLEN; ++s) {
        if (isA) {
            if (s < TLEN) {
                // stage x_{s+1} early (wave 0, lanes 0-31; 64B line -> L1)
                float xn = 0.0f;
                if (wv == 0 && h4 == 0 && s + 1 < TLEN)
                    xn = xg[(size_t)(b0 + nloc) * TLEN + s + 1];

                // GEMM1: k[0,112) of Rd = [h1_{s-1} | x_s | 1]
                half8 bf[7];
#pragma unroll
                for (int i = 0; i < 7; ++i)
                    bf[i] = *(const half8*)(Rd + 32 * i + 16 * h4);
                f32x16 a = {};
#pragma unroll
                for (int i = 0; i < 7; ++i)
                    a = __builtin_amdgcn_mfma_f32_32x32x16_f16(W[i], bf[i], a, 0, 0, 0);

                update_layer(a, Wr, 0);          // h1_s -> Wr lb[0,204)
                if (wv == 0 && h4 == 0 && s + 1 < TLEN)
                    *(unsigned*)(Wr + 204) = pack_hilo(xn);
            }
        } else {
            if (s >= 1) {
                // GEMM2: k[0,224) of Rd = [h1_{s-1} | x | 1 | h2_{s-2}]
                half8 bf[7];
#pragma unroll
                for (int i = 0; i < 7; ++i)
                    bf[i] = *(const half8*)(Rd + 32 * i + 16 * h4);
                f32x16 a = {};
#pragma unroll
                for (int i = 0; i < 7; ++i)
                    a = __builtin_amdgcn_mfma_f32_32x32x16_f16(W[i], bf[i], a, 0, 0, 0);
#pragma unroll
                for (int i = 0; i < 7; ++i)
                    bf[i] = *(const half8*)(Rd + 224 + 32 * i + 16 * h4);
#pragma unroll
                for (int i = 0; i < 7; ++i)
                    a = __builtin_amdgcn_mfma_f32_32x32x16_f16(W[7 + i], bf[i], a, 0, 0, 0);

                // y row n=204 = tile 6 local row 12 -> wave 13, h4==1, q=4
                if (wv == 13 && h4 == 1 && s >= 2)
                    out[(size_t)(b0 + nloc) * TLEN + (s - 2)] = a[4];

                update_layer(a, Wr, 224);        // h2_{s-1} -> Wr lb[224,428)
            }
        }
        __syncthreads();
        char* tmp = Rd; Rd = Wr; Wr = tmp;
    }

    // final y_{T-1} = blin + wlin . h2_{T-1}; h2_{2047} written at slot 2048
    // into that slot's Wr = buffer 1.
    if (tid < NB) {
        const char* r1 = hs + BUFB + tid * ROWB + ((tid & 7) << 4);
        float s = blin[0];
        for (int u = 0; u < NSZ; ++u) {
            const unsigned pk = *(const unsigned*)(r1 + 224 + 4 * u);
            const float hh = (float)__builtin_bit_cast(_Float16, (unsigned short)(pk & 0xffffu));
            const float hl = (float)__builtin_bit_cast(_Float16, (unsigned short)(pk >> 16));
            s = fmaf(wlin[u], hh + hl, s);
        }
        out[(size_t)(b0 + tid) * TLEN + (TLEN - 1)] = s;
    }
}

extern "C" void kernel_launch(void* const* d_in, const int* in_sizes, int n_in,
                              void* d_out, int out_size, void* d_ws, size_t ws_size,
                              hipStream_t stream) {
    (void)in_sizes; (void)n_in; (void)d_ws; (void)ws_size; (void)out_size;
    const float* xg   = (const float*)d_in[0];
    const float* wih1 = (const float*)d_in[1];
    const float* whh1 = (const float*)d_in[2];
    const float* bih1 = (const float*)d_in[3];
    const float* bhh1 = (const float*)d_in[4];
    const float* wih2 = (const float*)d_in[5];
    const float* whh2 = (const float*)d_in[6];
    const float* bih2 = (const float*)d_in[7];
    const float* bhh2 = (const float*)d_in[8];
    const float* wlin = (const float*)d_in[9];
    const float* blin = (const float*)d_in[10];
    // d_in[11] = future (static 0) -- ignored
    lstm2_kernel<<<dim3(BTOT / NB), dim3(NTHREADS), 0, stream>>>(
        xg, wih1, whh1, bih1, bhh1, wih2, whh2, bih2, bhh2, wlin, blin,
        (float*)d_out);
}

// Round 11
// 2804.094 us; speedup vs baseline: 1.8842x; 1.2047x over previous
//
#include <hip/hip_runtime.h>

// 2-layer LSTM (NS=51), B=8192, T=2048, future=0.
// Two-stage layer pipeline: waves 0-6 = layer 1 (GEMM1+update1), waves 7-13 =
// layer 2 (GEMM2+y+update2), one barrier per slot. 32x32x16 f16 MFMA,
// operand-swapped (A=weights stationary in VGPR, B=state in LDS).
// SINGLE-fp16 state (RTE) -- no hi/lo split: halves LDS traffic and MFMA
// count vs r10. Bias via constant-1 k-slot. fp32 accum + activations.
// Fallback if absmax > 9.6e-4: restore hi/lo split for h1 only.

#define TLEN 2048
#define BTOT 8192
#define NSZ  51
#define NB   32
#define NWAVES 14
#define NTHREADS (NWAVES * 64)   // 896
#define ROWB 272                 // bytes/state row; dword stride 68 == 4 mod 32
#define BUFB (NB * ROWB)         // 8704 B per buffer

// Row layout (fp16 index k, byte = 2k):
//  k[0,51)   h1 units          k=51 x        k=52 const 1.0 (bias)
//  k[53,56)  zero pad          k[56,107) h2  k[107,112) zero pad
//  bytes [224,272) unused (bank-spread padding)
// GEMM1 reads k[0,64) (4 frags; k>=53 weights are 0, data irrelevant).
// GEMM2 reads k[0,112) (7 frags; x slot weight 0).

typedef _Float16 half8  __attribute__((ext_vector_type(8)));
typedef float    f32x16 __attribute__((ext_vector_type(16)));

__global__ __launch_bounds__(NTHREADS, 4) void lstm2_kernel(
    const float* __restrict__ xg,    // [B][T]
    const float* __restrict__ wih1,  // [204][1]
    const float* __restrict__ whh1,  // [204][51]
    const float* __restrict__ bih1, const float* __restrict__ bhh1,
    const float* __restrict__ wih2,  // [204][51]
    const float* __restrict__ whh2,  // [204][51]
    const float* __restrict__ bih2, const float* __restrict__ bhh2,
    const float* __restrict__ wlin,  // [51]
    const float* __restrict__ blin,  // [1]
    float* __restrict__ out)         // [B][T]
{
    __shared__ char hs[2 * BUFB];    // 17 KB ping-pong state

    const int tid  = threadIdx.x;
    const int wv   = tid >> 6;       // wave 0..13
    const int lane = tid & 63;
    const int nloc = lane & 31;      // batch column / state row
    const int h4   = lane >> 5;      // k-octet selector
    const int b0   = blockIdx.x * NB;
    const bool isA = (wv < 7);       // layer-1 group
    const int tile = isA ? wv : wv - 7;

    for (int i = tid; i < 2 * BUFB / 4; i += NTHREADS) ((int*)hs)[i] = 0;

    const float LOG2E = 1.4426950408889634f;
    const int n = tile * 32 + nloc;               // interleaved gate row 4u+g
    const int Rrow = (n < 204) ? 51 * (n & 3) + (n >> 2) : 0;
    const float am = ((n & 3) == 2) ? (-2.0f * LOG2E) : (-LOG2E);

    // stationary weight fragments: A-waves use W[0..3], B-waves W[0..6]
    half8 W[7];
#pragma unroll
    for (int sN = 0; sN < 7; ++sN) {
        half8 v;
#pragma unroll
        for (int j = 0; j < 8; ++j) {
            const int k = 16 * sN + 8 * h4 + j;
            float w = 0.0f;
            if (isA) {
                if (n < 204) {
                    if (k < 51)        w = am * whh1[Rrow * 51 + k];
                    else if (k == 51)  w = am * wih1[Rrow];
                    else if (k == 52)  w = am * (bih1[Rrow] + bhh1[Rrow]);
                }
            } else {
                if (n < 204) {
                    if (k < 51)                   w = am * wih2[Rrow * 51 + k];
                    else if (k == 52)             w = am * (bih2[Rrow] + bhh2[Rrow]);
                    else if (k >= 56 && k < 107)  w = am * whh2[Rrow * 51 + (k - 56)];
                } else if (n == 204) {            // y row: blin + wlin . h2
                    if (k == 52)                  w = blin[0];
                    else if (k >= 56 && k < 107)  w = wlin[k - 56];
                }
            }
            v[j] = (_Float16)w;
        }
        W[sN] = v;
    }

    float cst[4] = {0, 0, 0, 0};     // c1 (A-waves) or c2 (B-waves)

    char* Rd = hs + nloc * ROWB;            // slot-0 read buffer (buf 0)
    char* Wr = hs + BUFB + nloc * ROWB;     // slot-0 write buffer (buf 1)

    __syncthreads();                 // zero-init visible
    if (tid < NB) {
        char* r0 = hs + tid * ROWB;
        *(unsigned short*)(r0 + 104) = 0x3C00;          // const 1.0, buf0
        *(unsigned short*)(r0 + BUFB + 104) = 0x3C00;   // const 1.0, buf1
        const float xv = xg[(size_t)(b0 + tid) * TLEN]; // x_0 -> buf0
        *(_Float16*)(r0 + 102) = (_Float16)xv;          // RTE
    }
    __syncthreads();

    // per-wave update: 4 acc quads -> 4 (b,u) tasks (guarded u<51), fp16 RTE out
    auto update_layer = [&](const f32x16& A, char* base, int boff) {
#pragma unroll
        for (int m = 0; m < 4; ++m) {
            const int u = 8 * tile + 2 * m + h4;
            if (u < NSZ) {
                const float gi = __builtin_amdgcn_rcpf(1.0f + __builtin_amdgcn_exp2f(A[4*m+0]));
                const float gf = __builtin_amdgcn_rcpf(1.0f + __builtin_amdgcn_exp2f(A[4*m+1]));
                const float gt = fmaf(2.0f, __builtin_amdgcn_rcpf(1.0f + __builtin_amdgcn_exp2f(A[4*m+2])), -1.0f);
                const float go = __builtin_amdgcn_rcpf(1.0f + __builtin_amdgcn_exp2f(A[4*m+3]));
                const float cn = fmaf(gf, cst[m], gi * gt);
                cst[m] = cn;
                const float ee = __builtin_amdgcn_exp2f(-2.8853900817779268f * cn);
                const float th = fmaf(2.0f, __builtin_amdgcn_rcpf(1.0f + ee), -1.0f);
                const float hv = go * th;
                *(_Float16*)(base + boff + 2 * u) = (_Float16)hv;  // RTE
            }
        }
    };

    for (int s = 0; s <= TLEN; ++s) {
        if (isA) {
            if (s < TLEN) {
                // stage x_{s+1} early (wave 0, lanes 0-31 own batch rows)
                float xn = 0.0f;
                if (wv == 0 && h4 == 0 && s + 1 < TLEN)
                    xn = xg[(size_t)(b0 + nloc) * TLEN + s + 1];

                // GEMM1: k[0,64) of Rd = [h1_{s-1} | x_s | 1 | ...]
                half8 bf[4];
#pragma unroll
                for (int i = 0; i < 4; ++i)
                    bf[i] = *(const half8*)(Rd + 32 * i + 16 * h4);
                f32x16 a = {};
#pragma unroll
                for (int i = 0; i < 4; ++i)
                    a = __builtin_amdgcn_mfma_f32_32x32x16_f16(W[i], bf[i], a, 0, 0, 0);

                update_layer(a, Wr, 0);          // h1_s -> Wr k[0,51)
                if (wv == 0 && h4 == 0 && s + 1 < TLEN)
                    *(_Float16*)(Wr + 102) = (_Float16)xn;
            }
        } else {
            if (s >= 1) {
                // GEMM2: k[0,112) of Rd = [h1_{s-1} | x | 1 | pad | h2_{s-2}]
                half8 bf[7];
#pragma unroll
                for (int i = 0; i < 7; ++i)
                    bf[i] = *(const half8*)(Rd + 32 * i + 16 * h4);
                f32x16 a = {};
#pragma unroll
                for (int i = 0; i < 7; ++i)
                    a = __builtin_amdgcn_mfma_f32_32x32x16_f16(W[i], bf[i], a, 0, 0, 0);

                // y row n=204 = tile 6 local row 12 -> wave 13, h4==1, q=4
                if (wv == 13 && h4 == 1 && s >= 2)
                    out[(size_t)(b0 + nloc) * TLEN + (s - 2)] = a[4];

                update_layer(a, Wr, 112);        // h2_{s-1} -> Wr k[56,107)
            }
        }
        __syncthreads();
        char* tmp = Rd; Rd = Wr; Wr = tmp;
    }

    // final y_{T-1}: h2_{2047} written at slot 2048 into buf 1
    if (tid < NB) {
        const char* r1 = hs + BUFB + tid * ROWB;
        float s = blin[0];
        for (int u = 0; u < NSZ; ++u)
            s = fmaf(wlin[u], (float)*(const _Float16*)(r1 + 112 + 2 * u), s);
        out[(size_t)(b0 + tid) * TLEN + (TLEN - 1)] = s;
    }
}

extern "C" void kernel_launch(void* const* d_in, const int* in_sizes, int n_in,
                              void* d_out, int out_size, void* d_ws, size_t ws_size,
                              hipStream_t stream) {
    (void)in_sizes; (void)n_in; (void)d_ws; (void)ws_size; (void)out_size;
    const float* xg   = (const float*)d_in[0];
    const float* wih1 = (const float*)d_in[1];
    const float* whh1 = (const float*)d_in[2];
    const float* bih1 = (const float*)d_in[3];
    const float* bhh1 = (const float*)d_in[4];
    const float* wih2 = (const float*)d_in[5];
    const float* whh2 = (const float*)d_in[6];
    const float* bih2 = (const float*)d_in[7];
    const float* bhh2 = (const float*)d_in[8];
    const float* wlin = (const float*)d_in[9];
    const float* blin = (const float*)d_in[10];
    // d_in[11] = future (static 0) -- ignored
    lstm2_kernel<<<dim3(BTOT / NB), dim3(NTHREADS), 0, stream>>>(
        xg, wih1, whh1, bih1, bhh1, wih2, whh2, bih2, bhh2, wlin, blin,
        (float*)d_out);
}